// Round 10
// baseline (1169.123 us; speedup 1.0000x reference)
//
#include <hip/hip_runtime.h>
#include <hip/hip_cooperative_groups.h>

namespace cg = cooperative_groups;

// ---------------- problem constants ----------------
#define NN 100000      // nodes
#define NE 1600000     // edges (without self loops)
#define DD 128         // feature dim
#define EPSV 1e-5f

#define NSTRIP 6250            // NN/16 row-strips for MFMA gemms
#define GBV 1563               // ceil(NSTRIP/4) virtual gemm blocks

// bucket sort: 196 buckets of 512 nodes; 782 hist/place blocks of 2048 edges
#define BSHIFT 9
#define NBUCK 196
#define EPB 2048
#define NHB 782

#define NSHARD 32              // stats atomic shards
#define STATS_F (4 * NSHARD * 128)   // 2 stages x (sum|sq)[32][128]

#define GRID 768               // 256 CU x 3 blocks/CU (cooperative co-residency)
#define TPB 256

typedef __attribute__((ext_vector_type(8))) __bf16 bf16x8;
typedef __attribute__((ext_vector_type(4))) float f32x4;

union BF8 {
    ushort  us[8];
    uint    ui[4];
    uint4   u4;
    bf16x8  v;
};

__device__ __forceinline__ ushort f2bf(float f) {   // RNE fp32 -> bf16 bits
    uint u = __float_as_uint(f);
    return (ushort)((u + 0x7fffu + ((u >> 16) & 1u)) >> 16);
}
__device__ __forceinline__ float bflo(uint u) { return __uint_as_float(u << 16); }
__device__ __forceinline__ float bfhi(uint u) { return __uint_as_float(u & 0xffff0000u); }

// ============================================================================
//                       FALLBACK multi-kernel path (R8)
// ============================================================================

__global__ void k_prepw3(const float* __restrict__ WA, const float* __restrict__ WB,
                         const float* __restrict__ WC, ushort* __restrict__ Wf,
                         int* __restrict__ bucket_cnt, float* __restrict__ statsG) {
    int gid = blockIdx.x * 256 + threadIdx.x;
    if (gid < 256) bucket_cnt[gid] = 0;
    for (int i = gid; i < STATS_F; i += 24 * 256) statsG[i] = 0.f;

    int which = blockIdx.x >> 3;
    const float* W = (which == 0) ? WA : ((which == 1) ? WB : WC);
    int t = (blockIdx.x & 7) * 256 + threadIdx.x;
    int lane = t & 63;
    int kt = (t >> 6) & 3;
    int nt = t >> 8;
    int quad = lane >> 4;
    int n = nt * 16 + (lane & 15);
    BF8 f;
    #pragma unroll
    for (int j = 0; j < 8; j++)
        f.us[j] = f2bf(W[(kt * 32 + quad * 8 + j) * DD + n]);
    ((uint4*)(Wf + (size_t)which * 2048 * 8))[t] = f.u4;
}

__global__ __launch_bounds__(256)
void kb_hist(const int* __restrict__ col, int* __restrict__ bucket_cnt,
             int* __restrict__ blk_off) {
    __shared__ int h[256];
    int t = threadIdx.x;
    h[t] = 0;
    __syncthreads();
    int e0 = blockIdx.x * EPB;
    #pragma unroll
    for (int j = 0; j < 8; j++) {
        int e = e0 + t + j * 256;
        if (e < NE) atomicAdd(&h[col[e] >> BSHIFT], 1);
    }
    __syncthreads();
    int c = h[t];
    blk_off[blockIdx.x * 256 + t] = c ? atomicAdd(&bucket_cnt[t], c) : 0;
}

__global__ __launch_bounds__(256)
void kb_place(const int* __restrict__ row, const int* __restrict__ col,
              const int* __restrict__ bucket_cnt, const int* __restrict__ blk_off,
              int* __restrict__ bucket_base, uint* __restrict__ ebuf) {
    __shared__ int s[256];
    __shared__ int cur[256];
    int t = threadIdx.x;
    int v = bucket_cnt[t];
    s[t] = v;
    __syncthreads();
    for (int off = 1; off < 256; off <<= 1) {
        int u = (t >= off) ? s[t - off] : 0;
        __syncthreads();
        s[t] += u;
        __syncthreads();
    }
    int base = s[t] - v;
    cur[t] = base + blk_off[blockIdx.x * 256 + t];
    if (blockIdx.x == 0) {
        bucket_base[t] = base;
        if (t == 255) bucket_base[256] = s[255];
    }
    __syncthreads();
    int e0 = blockIdx.x * EPB;
    #pragma unroll
    for (int j = 0; j < 8; j++) {
        int e = e0 + t + j * 256;
        if (e < NE) {
            int c = col[e];
            int pos = atomicAdd(&cur[c >> BSHIFT], 1);
            ebuf[pos] = ((uint)row[e] << BSHIFT) | (uint)(c & ((1 << BSHIFT) - 1));
        }
    }
}

__global__ __launch_bounds__(512)
void kb_fin(const uint* __restrict__ ebuf, const int* __restrict__ bucket_base,
            int* __restrict__ row_ptr, float* __restrict__ dinv,
            int* __restrict__ csr) {
    __shared__ int deg[512];
    __shared__ int scn[512];
    int b = blockIdx.x;
    int n0 = b << BSHIFT;
    int t = threadIdx.x;
    deg[t] = 0;
    __syncthreads();
    int s = bucket_base[b], e = bucket_base[b + 1];
    for (int p = s + t; p < e; p += 512)
        atomicAdd(&deg[ebuf[p] & 511u], 1);
    __syncthreads();
    int d = deg[t];
    scn[t] = d;
    __syncthreads();
    for (int off = 1; off < 512; off <<= 1) {
        int u = (t >= off) ? scn[t - off] : 0;
        __syncthreads();
        scn[t] += u;
        __syncthreads();
    }
    int base = s + scn[t] - d;
    int node = n0 + t;
    if (node < NN) { row_ptr[node] = base; dinv[node] = rsqrtf((float)(d + 1)); }
    __syncthreads();
    deg[t] = base;
    __syncthreads();
    for (int p = s + t; p < e; p += 512) {
        uint r = ebuf[p];
        int pos = atomicAdd(&deg[r & 511u], 1);
        csr[pos] = (int)(r >> BSHIFT);
    }
    if (b == 0 && t == 0) row_ptr[NN] = NE;
}

__global__ __launch_bounds__(256)
void k_gemmA(const float* __restrict__ X, const ushort* __restrict__ Wf,
             const float* __restrict__ dinv, ushort* __restrict__ Y) {
    int strip = blockIdx.x * 4 + (threadIdx.x >> 6);
    if (strip >= NSTRIP) return;
    int lane = threadIdx.x & 63;
    int quad = lane >> 4;
    int m = lane & 15;
    int row = strip * 16 + m;

    BF8 a[4];
    #pragma unroll
    for (int kt = 0; kt < 4; kt++) {
        const float* xp = X + (size_t)row * DD + kt * 32 + quad * 8;
        float4 v0 = *(const float4*)xp;
        float4 v1 = *(const float4*)(xp + 4);
        a[kt].us[0] = f2bf(v0.x); a[kt].us[1] = f2bf(v0.y);
        a[kt].us[2] = f2bf(v0.z); a[kt].us[3] = f2bf(v0.w);
        a[kt].us[4] = f2bf(v1.x); a[kt].us[5] = f2bf(v1.y);
        a[kt].us[6] = f2bf(v1.z); a[kt].us[7] = f2bf(v1.w);
    }

    float4 dv = *(const float4*)(dinv + strip * 16 + quad * 4);
    float dvr[4] = {dv.x, dv.y, dv.z, dv.w};

    #pragma unroll
    for (int nt = 0; nt < 8; nt++) {
        f32x4 acc = {0.f, 0.f, 0.f, 0.f};
        #pragma unroll
        for (int kt = 0; kt < 4; kt++) {
            BF8 b;
            b.u4 = ((const uint4*)Wf)[(nt * 4 + kt) * 64 + lane];
            acc = __builtin_amdgcn_mfma_f32_16x16x32_bf16(a[kt].v, b.v, acc, 0, 0, 0);
        }
        int colg = nt * 16 + m;
        #pragma unroll
        for (int r = 0; r < 4; r++)
            Y[(size_t)(strip * 16 + quad * 4 + r) * DD + colg] = f2bf(acc[r] * dvr[r]);
    }
}

__global__ __launch_bounds__(256)
void k_gemmB(const uint* __restrict__ Xp, const ushort* __restrict__ Wf,
             const float* __restrict__ psum, const float* __restrict__ psq,
             const float* __restrict__ gw, const float* __restrict__ gb,
             const float* __restrict__ ga,
             const float* __restrict__ dinv, ushort* __restrict__ Y) {
    __shared__ float smul[128], sadd[128];
    {
        int f = threadIdx.x;
        if (f < 128) {
            float s = 0.f, q = 0.f;
            #pragma unroll
            for (int sh = 0; sh < NSHARD; sh++) { s += psum[sh * 128 + f]; q += psq[sh * 128 + f]; }
            const float invn = 1.0f / (float)NN;
            float mm = s * invn, ex2 = q * invn, av = ga[f];
            float var = ex2 - mm * mm * (2.f * av - av * av);
            float inv = rsqrtf(var + EPSV);
            smul[f] = gw[f] * inv;
            sadd[f] = gb[f] - gw[f] * inv * av * mm;
        }
    }
    __syncthreads();
    int strip = blockIdx.x * 4 + (threadIdx.x >> 6);
    if (strip >= NSTRIP) return;
    int lane = threadIdx.x & 63;
    int quad = lane >> 4;
    int m = lane & 15;
    int row = strip * 16 + m;

    BF8 a[4];
    #pragma unroll
    for (int kt = 0; kt < 4; kt++) {
        int f = kt * 32 + quad * 8;
        uint4 xu = *(const uint4*)(Xp + (size_t)row * 64 + kt * 16 + quad * 4);
        float4 m0 = *(const float4*)(smul + f);
        float4 m1 = *(const float4*)(smul + f + 4);
        float4 a0 = *(const float4*)(sadd + f);
        float4 a1 = *(const float4*)(sadd + f + 4);
        uint xs[4] = {xu.x, xu.y, xu.z, xu.w};
        float mm[8] = {m0.x, m0.y, m0.z, m0.w, m1.x, m1.y, m1.z, m1.w};
        float aa[8] = {a0.x, a0.y, a0.z, a0.w, a1.x, a1.y, a1.z, a1.w};
        #pragma unroll
        for (int p = 0; p < 4; p++) {
            float lo = bflo(xs[p]), hi = bfhi(xs[p]);
            a[kt].us[2 * p]     = f2bf(fmaxf(0.f, fmaf(lo, mm[2 * p],     aa[2 * p])));
            a[kt].us[2 * p + 1] = f2bf(fmaxf(0.f, fmaf(hi, mm[2 * p + 1], aa[2 * p + 1])));
        }
    }

    float4 dv = *(const float4*)(dinv + strip * 16 + quad * 4);
    float dvr[4] = {dv.x, dv.y, dv.z, dv.w};

    #pragma unroll
    for (int nt = 0; nt < 8; nt++) {
        f32x4 acc = {0.f, 0.f, 0.f, 0.f};
        #pragma unroll
        for (int kt = 0; kt < 4; kt++) {
            BF8 b;
            b.u4 = ((const uint4*)Wf)[(nt * 4 + kt) * 64 + lane];
            acc = __builtin_amdgcn_mfma_f32_16x16x32_bf16(a[kt].v, b.v, acc, 0, 0, 0);
        }
        int colg = nt * 16 + m;
        #pragma unroll
        for (int r = 0; r < 4; r++)
            Y[(size_t)(strip * 16 + quad * 4 + r) * DD + colg] = f2bf(acc[r] * dvr[r]);
    }
}

__global__ __launch_bounds__(512)
void k_agg2(const uint* __restrict__ H2,
            const int* __restrict__ row_ptr, const int* __restrict__ csr,
            const float* __restrict__ dinv,
            const float* __restrict__ bias, uint* __restrict__ Y2,
            float* __restrict__ psumG, float* __restrict__ psqG) {
    const int lane = threadIdx.x & 63;
    const int wid  = threadIdx.x >> 6;
    const int i = __builtin_amdgcn_readfirstlane(blockIdx.x * 8 + wid);
    const int p0 = row_ptr[i], p1 = row_ptr[i + 1];
    const float di = dinv[i];
    uint su = H2[(size_t)i * 64 + lane];
    float a0 = bflo(su), a1 = bfhi(su);
    float b0 = 0.f, b1 = 0.f, c0 = 0.f, c1 = 0.f, d0 = 0.f, d1 = 0.f;
    int p = p0;
    for (; p + 7 < p1; p += 8) {
        int s0 = csr[p],     s1 = csr[p + 1], s2 = csr[p + 2], s3 = csr[p + 3];
        int s4 = csr[p + 4], s5 = csr[p + 5], s6 = csr[p + 6], s7 = csr[p + 7];
        uint h0 = H2[(size_t)s0 * 64 + lane];
        uint h1 = H2[(size_t)s1 * 64 + lane];
        uint h2 = H2[(size_t)s2 * 64 + lane];
        uint h3 = H2[(size_t)s3 * 64 + lane];
        uint h4 = H2[(size_t)s4 * 64 + lane];
        uint h5 = H2[(size_t)s5 * 64 + lane];
        uint h6 = H2[(size_t)s6 * 64 + lane];
        uint h7 = H2[(size_t)s7 * 64 + lane];
        a0 += bflo(h0); a1 += bfhi(h0);
        b0 += bflo(h1); b1 += bfhi(h1);
        c0 += bflo(h2); c1 += bfhi(h2);
        d0 += bflo(h3); d1 += bfhi(h3);
        a0 += bflo(h4); a1 += bfhi(h4);
        b0 += bflo(h5); b1 += bfhi(h5);
        c0 += bflo(h6); c1 += bfhi(h6);
        d0 += bflo(h7); d1 += bfhi(h7);
    }
    for (; p + 3 < p1; p += 4) {
        int s0 = csr[p], s1 = csr[p + 1], s2 = csr[p + 2], s3 = csr[p + 3];
        uint h0 = H2[(size_t)s0 * 64 + lane];
        uint h1 = H2[(size_t)s1 * 64 + lane];
        uint h2 = H2[(size_t)s2 * 64 + lane];
        uint h3 = H2[(size_t)s3 * 64 + lane];
        a0 += bflo(h0); a1 += bfhi(h0);
        b0 += bflo(h1); b1 += bfhi(h1);
        c0 += bflo(h2); c1 += bfhi(h2);
        d0 += bflo(h3); d1 += bfhi(h3);
    }
    for (; p < p1; p++) {
        uint h0 = H2[(size_t)csr[p] * 64 + lane];
        a0 += bflo(h0); a1 += bfhi(h0);
    }
    float2 bb = *(const float2*)(bias + 2 * lane);
    float r0 = fmaf((a0 + b0) + (c0 + d0), di, bb.x);
    float r1 = fmaf((a1 + b1) + (c1 + d1), di, bb.y);
    Y2[(size_t)i * 64 + lane] = (uint)f2bf(r0) | ((uint)f2bf(r1) << 16);

    __shared__ float ls[8][128], lq[8][128];
    ls[wid][2 * lane]     = r0;      ls[wid][2 * lane + 1] = r1;
    lq[wid][2 * lane]     = r0 * r0; lq[wid][2 * lane + 1] = r1 * r1;
    __syncthreads();
    if (threadIdx.x < 128) {
        int f = threadIdx.x;
        float s = ((ls[0][f] + ls[1][f]) + (ls[2][f] + ls[3][f]))
                + ((ls[4][f] + ls[5][f]) + (ls[6][f] + ls[7][f]));
        float q = ((lq[0][f] + lq[1][f]) + (lq[2][f] + lq[3][f]))
                + ((lq[4][f] + lq[5][f]) + (lq[6][f] + lq[7][f]));
        int sh = (blockIdx.x & (NSHARD - 1)) * 128 + f;
        atomicAdd(&psumG[sh], s);
        atomicAdd(&psqG[sh], q);
    }
}

__global__ __launch_bounds__(256)
void k_mlp(const uint* __restrict__ Xp, const ushort* __restrict__ Wf,
           const float* __restrict__ psum, const float* __restrict__ psq,
           const float* __restrict__ gw, const float* __restrict__ gb,
           const float* __restrict__ ga,
           const float* __restrict__ b0h, const float* __restrict__ v1,
           const float* __restrict__ b1, float* __restrict__ out) {
    __shared__ float smul[128], sadd[128];
    {
        int f = threadIdx.x;
        if (f < 128) {
            float s = 0.f, q = 0.f;
            #pragma unroll
            for (int sh = 0; sh < NSHARD; sh++) { s += psum[sh * 128 + f]; q += psq[sh * 128 + f]; }
            const float invn = 1.0f / (float)NN;
            float mm = s * invn, ex2 = q * invn, av = ga[f];
            float var = ex2 - mm * mm * (2.f * av - av * av);
            float inv = rsqrtf(var + EPSV);
            smul[f] = gw[f] * inv;
            sadd[f] = gb[f] - gw[f] * inv * av * mm;
        }
    }
    __syncthreads();
    int strip = blockIdx.x * 4 + (threadIdx.x >> 6);
    if (strip >= NSTRIP) return;
    int lane = threadIdx.x & 63;
    int quad = lane >> 4;
    int m = lane & 15;
    int row = strip * 16 + m;

    BF8 a[4];
    #pragma unroll
    for (int kt = 0; kt < 4; kt++) {
        int f = kt * 32 + quad * 8;
        uint4 xu = *(const uint4*)(Xp + (size_t)row * 64 + kt * 16 + quad * 4);
        float4 m0 = *(const float4*)(smul + f);
        float4 m1 = *(const float4*)(smul + f + 4);
        float4 a0 = *(const float4*)(sadd + f);
        float4 a1 = *(const float4*)(sadd + f + 4);
        uint xs[4] = {xu.x, xu.y, xu.z, xu.w};
        float mm[8] = {m0.x, m0.y, m0.z, m0.w, m1.x, m1.y, m1.z, m1.w};
        float aa[8] = {a0.x, a0.y, a0.z, a0.w, a1.x, a1.y, a1.z, a1.w};
        #pragma unroll
        for (int p = 0; p < 4; p++) {
            float lo = bflo(xs[p]), hi = bfhi(xs[p]);
            a[kt].us[2 * p]     = f2bf(fmaxf(0.f, fmaf(lo, mm[2 * p],     aa[2 * p])));
            a[kt].us[2 * p + 1] = f2bf(fmaxf(0.f, fmaf(hi, mm[2 * p + 1], aa[2 * p + 1])));
        }
    }

    float part[4] = {0.f, 0.f, 0.f, 0.f};
    #pragma unroll
    for (int nt = 0; nt < 8; nt++) {
        f32x4 acc = {0.f, 0.f, 0.f, 0.f};
        #pragma unroll
        for (int kt = 0; kt < 4; kt++) {
            BF8 b;
            b.u4 = ((const uint4*)Wf)[(nt * 4 + kt) * 64 + lane];
            acc = __builtin_amdgcn_mfma_f32_16x16x32_bf16(a[kt].v, b.v, acc, 0, 0, 0);
        }
        int colg = nt * 16 + m;
        float bb = b0h[colg];
        float vv = v1[colg];
        #pragma unroll
        for (int r = 0; r < 4; r++)
            part[r] = fmaf(fmaxf(0.f, acc[r] + bb), vv, part[r]);
    }
    #pragma unroll
    for (int r = 0; r < 4; r++) {
        #pragma unroll
        for (int off = 1; off < 16; off <<= 1)
            part[r] += __shfl_xor(part[r], off, 64);
    }
    if (m == 0) {
        float ob = b1[0];
        #pragma unroll
        for (int r = 0; r < 4; r++)
            out[strip * 16 + quad * 4 + r] = part[r] + ob;
    }
}

// ============================================================================
//                        Cooperative mega-kernel path
// ============================================================================

struct MegaP {
    const float* x;
    const int*   row;
    const int*   col;
    const float* b0;  const float* b1;
    const float* gn0w; const float* gn0b; const float* gn0a;
    const float* gn1w; const float* gn1b; const float* gn1a;
    const float* lin0b; const float* lin1w; const float* lin1b;
    const float* W0; const float* W1; const float* lin0w;
    float* out;
    ushort* bufA; ushort* bufB;
    int* csr; uint* ebuf; int* blk_off; int* bucket_cnt; int* bucket_base;
    int* row_ptr; float* dinv; float* statsG; ushort* Wf;
};

__device__ __forceinline__ void norm_params(const float* __restrict__ psum,
                                            const float* __restrict__ psq,
                                            const float* __restrict__ gw,
                                            const float* __restrict__ gb,
                                            const float* __restrict__ ga,
                                            float* smul, float* sadd, int t) {
    if (t < 128) {
        float s = 0.f, q = 0.f;
        #pragma unroll
        for (int sh = 0; sh < NSHARD; sh++) { s += psum[sh * 128 + t]; q += psq[sh * 128 + t]; }
        const float invn = 1.0f / (float)NN;
        float mm = s * invn, ex2 = q * invn, av = ga[t];
        float var = ex2 - mm * mm * (2.f * av - av * av);
        float inv = rsqrtf(var + EPSV);
        smul[t] = gw[t] * inv;
        sadd[t] = gb[t] - gw[t] * inv * av * mm;
    }
    __syncthreads();
}

__device__ __forceinline__ void agg_phase(const uint* __restrict__ H2,
                                          uint* __restrict__ Y2,
                                          const int* __restrict__ row_ptr,
                                          const int* __restrict__ csr,
                                          const float* __restrict__ dinv,
                                          const float* __restrict__ bias,
                                          float* __restrict__ psumG,
                                          float* __restrict__ psqG,
                                          char* smemraw, int t, int bid) {
    const int lane = t & 63;
    const int wid  = t >> 6;
    const float2 bb = *(const float2*)(bias + 2 * lane);
    float ss0 = 0.f, ss1 = 0.f, sq0 = 0.f, sq1 = 0.f;
    for (int vb = bid; vb < NN / 4; vb += GRID) {
        const int i = __builtin_amdgcn_readfirstlane(vb * 4 + wid);
        const int p0 = row_ptr[i], p1 = row_ptr[i + 1];
        const float di = dinv[i];
        uint su = H2[(size_t)i * 64 + lane];
        float a0 = bflo(su), a1 = bfhi(su);
        float b0 = 0.f, b1 = 0.f, c0 = 0.f, c1 = 0.f, d0 = 0.f, d1 = 0.f;
        int p = p0;
        for (; p + 15 < p1; p += 16) {                 // 16 loads in flight
            int s0 = csr[p],      s1 = csr[p + 1],  s2 = csr[p + 2],  s3 = csr[p + 3];
            int s4 = csr[p + 4],  s5 = csr[p + 5],  s6 = csr[p + 6],  s7 = csr[p + 7];
            int s8 = csr[p + 8],  s9 = csr[p + 9],  sa = csr[p + 10], sb = csr[p + 11];
            int sc = csr[p + 12], sd = csr[p + 13], se = csr[p + 14], sf = csr[p + 15];
            uint h0 = H2[(size_t)s0 * 64 + lane];
            uint h1 = H2[(size_t)s1 * 64 + lane];
            uint h2 = H2[(size_t)s2 * 64 + lane];
            uint h3 = H2[(size_t)s3 * 64 + lane];
            uint h4 = H2[(size_t)s4 * 64 + lane];
            uint h5 = H2[(size_t)s5 * 64 + lane];
            uint h6 = H2[(size_t)s6 * 64 + lane];
            uint h7 = H2[(size_t)s7 * 64 + lane];
            uint h8 = H2[(size_t)s8 * 64 + lane];
            uint h9 = H2[(size_t)s9 * 64 + lane];
            uint ha = H2[(size_t)sa * 64 + lane];
            uint hb = H2[(size_t)sb * 64 + lane];
            uint hc = H2[(size_t)sc * 64 + lane];
            uint hd = H2[(size_t)sd * 64 + lane];
            uint he = H2[(size_t)se * 64 + lane];
            uint hf = H2[(size_t)sf * 64 + lane];
            a0 += bflo(h0); a1 += bfhi(h0);
            b0 += bflo(h1); b1 += bfhi(h1);
            c0 += bflo(h2); c1 += bfhi(h2);
            d0 += bflo(h3); d1 += bfhi(h3);
            a0 += bflo(h4); a1 += bfhi(h4);
            b0 += bflo(h5); b1 += bfhi(h5);
            c0 += bflo(h6); c1 += bfhi(h6);
            d0 += bflo(h7); d1 += bfhi(h7);
            a0 += bflo(h8); a1 += bfhi(h8);
            b0 += bflo(h9); b1 += bfhi(h9);
            c0 += bflo(ha); c1 += bfhi(ha);
            d0 += bflo(hb); d1 += bfhi(hb);
            a0 += bflo(hc); a1 += bfhi(hc);
            b0 += bflo(hd); b1 += bfhi(hd);
            c0 += bflo(he); c1 += bfhi(he);
            d0 += bflo(hf); d1 += bfhi(hf);
        }
        for (; p + 3 < p1; p += 4) {
            int s0 = csr[p], s1 = csr[p + 1], s2 = csr[p + 2], s3 = csr[p + 3];
            uint h0 = H2[(size_t)s0 * 64 + lane];
            uint h1 = H2[(size_t)s1 * 64 + lane];
            uint h2 = H2[(size_t)s2 * 64 + lane];
            uint h3 = H2[(size_t)s3 * 64 + lane];
            a0 += bflo(h0); a1 += bfhi(h0);
            b0 += bflo(h1); b1 += bfhi(h1);
            c0 += bflo(h2); c1 += bfhi(h2);
            d0 += bflo(h3); d1 += bfhi(h3);
        }
        for (; p < p1; p++) {
            uint h0 = H2[(size_t)csr[p] * 64 + lane];
            a0 += bflo(h0); a1 += bfhi(h0);
        }
        float r0 = fmaf((a0 + b0) + (c0 + d0), di, bb.x);
        float r1 = fmaf((a1 + b1) + (c1 + d1), di, bb.y);
        Y2[(size_t)i * 64 + lane] = (uint)f2bf(r0) | ((uint)f2bf(r1) << 16);
        ss0 += r0; sq0 = fmaf(r0, r0, sq0);
        ss1 += r1; sq1 = fmaf(r1, r1, sq1);
    }
    float* ls = (float*)smemraw;                       // [4][128]
    float* lq = ls + 512;                              // [4][128]
    ls[wid * 128 + 2 * lane]     = ss0; ls[wid * 128 + 2 * lane + 1] = ss1;
    lq[wid * 128 + 2 * lane]     = sq0; lq[wid * 128 + 2 * lane + 1] = sq1;
    __syncthreads();
    if (t < 128) {
        float s = (ls[t] + ls[128 + t]) + (ls[256 + t] + ls[384 + t]);
        float q = (lq[t] + lq[128 + t]) + (lq[256 + t] + lq[384 + t]);
        int sh = (bid & (NSHARD - 1)) * 128 + t;
        atomicAdd(&psumG[sh], s);
        atomicAdd(&psqG[sh], q);
    }
    __syncthreads();
}

__global__ __launch_bounds__(TPB, 3)
void k_mega(MegaP P) {
    cg::grid_group grid = cg::this_grid();
    __shared__ __align__(16) char smemraw[4352];
    const int t   = threadIdx.x;
    const int bid = blockIdx.x;
    const int gtid = bid * TPB + t;
    const int lane = t & 63;
    const int wid  = t >> 6;
    const int quad = lane >> 4;
    const int m    = lane & 15;

    const ushort* Wf0 = P.Wf;
    const ushort* Wf1 = P.Wf + 2048 * 8;
    const ushort* Wf2 = P.Wf + 2 * 2048 * 8;
    float* ps0 = P.statsG;
    float* pq0 = P.statsG + NSHARD * 128;
    float* ps1 = P.statsG + 2 * NSHARD * 128;
    float* pq1 = P.statsG + 3 * NSHARD * 128;

    // ---- P0: zero scratch + weight prep ----
    if (gtid < 256) P.bucket_cnt[gtid] = 0;
    if (gtid < STATS_F) P.statsG[gtid] = 0.f;
    if (gtid < 6144) {
        int which = gtid >> 11;
        const float* W = (which == 0) ? P.W0 : ((which == 1) ? P.W1 : P.lin0w);
        int tt = gtid & 2047;
        int l2 = tt & 63;
        int kt = (tt >> 6) & 3;
        int nt = tt >> 8;
        int q2 = l2 >> 4;
        int n = nt * 16 + (l2 & 15);
        BF8 f;
        #pragma unroll
        for (int j = 0; j < 8; j++)
            f.us[j] = f2bf(W[(kt * 32 + q2 * 8 + j) * DD + n]);
        ((uint4*)(P.Wf + (size_t)which * 2048 * 8))[tt] = f.u4;
    }
    grid.sync();

    // ---- P1: bucket histogram (grid-strided: NHB=782 > GRID=768) ----
    for (int vb = bid; vb < NHB; vb += GRID) {
        int* h = (int*)smemraw;
        h[t] = 0;
        __syncthreads();
        int e0 = vb * EPB;
        #pragma unroll
        for (int j = 0; j < 8; j++) {
            int e = e0 + t + j * 256;
            if (e < NE) atomicAdd(&h[P.col[e] >> BSHIFT], 1);
        }
        __syncthreads();
        int c = h[t];
        P.blk_off[vb * 256 + t] = c ? atomicAdd(&P.bucket_cnt[t], c) : 0;
    }
    grid.sync();

    // ---- P2: place (scan fused; vb==0 publishes bucket_base; grid-strided) ----
    for (int vb = bid; vb < NHB; vb += GRID) {
        int* s   = (int*)smemraw;
        int* cur = s + 256;
        int v = P.bucket_cnt[t];
        s[t] = v;
        __syncthreads();
        for (int off = 1; off < 256; off <<= 1) {
            int u = (t >= off) ? s[t - off] : 0;
            __syncthreads();
            s[t] += u;
            __syncthreads();
        }
        int base = s[t] - v;
        cur[t] = base + P.blk_off[vb * 256 + t];
        if (vb == 0) {
            P.bucket_base[t] = base;
            if (t == 255) P.bucket_base[256] = s[255];
        }
        __syncthreads();
        int e0 = vb * EPB;
        #pragma unroll
        for (int j = 0; j < 8; j++) {
            int e = e0 + t + j * 256;
            if (e < NE) {
                int c = P.col[e];
                int pos = atomicAdd(&cur[c >> BSHIFT], 1);
                P.ebuf[pos] = ((uint)P.row[e] << BSHIFT) | (uint)(c & ((1 << BSHIFT) - 1));
            }
        }
        __syncthreads();     // protect cur[] before next iteration's scan rewrite
    }
    grid.sync();

    // ---- P3: per-bucket finalize (row_ptr / dinv / csr) ----
    if (bid < NBUCK) {
        int* deg = (int*)smemraw;          // 512 ints
        int* scn = deg + 512;              // 256 ints
        int n0 = bid << BSHIFT;
        deg[t] = 0; deg[t + 256] = 0;
        __syncthreads();
        int s = P.bucket_base[bid], e = P.bucket_base[bid + 1];
        for (int p = s + t; p < e; p += 256)
            atomicAdd(&deg[P.ebuf[p] & 511u], 1);
        __syncthreads();
        int d0 = deg[2 * t], d1 = deg[2 * t + 1];
        int pairsum = d0 + d1;
        scn[t] = pairsum;
        __syncthreads();
        for (int off = 1; off < 256; off <<= 1) {
            int u = (t >= off) ? scn[t - off] : 0;
            __syncthreads();
            scn[t] += u;
            __syncthreads();
        }
        int base = s + scn[t] - pairsum;
        int node0 = n0 + 2 * t;
        if (node0 < NN)     { P.row_ptr[node0]     = base;      P.dinv[node0]     = rsqrtf((float)(d0 + 1)); }
        if (node0 + 1 < NN) { P.row_ptr[node0 + 1] = base + d0; P.dinv[node0 + 1] = rsqrtf((float)(d1 + 1)); }
        __syncthreads();
        deg[2 * t] = base;
        deg[2 * t + 1] = base + d0;
        __syncthreads();
        for (int p = s + t; p < e; p += 256) {
            uint r = P.ebuf[p];
            int pos = atomicAdd(&deg[r & 511u], 1);
            P.csr[pos] = (int)(r >> BSHIFT);
        }
        if (bid == 0 && t == 0) P.row_ptr[NN] = NE;
    }
    grid.sync();

    // ---- P4: GEMM1 ----
    for (int vb = bid; vb < GBV; vb += GRID) {
        int strip = vb * 4 + wid;
        if (strip >= NSTRIP) continue;
        int row = strip * 16 + m;
        BF8 a[4];
        #pragma unroll
        for (int kt = 0; kt < 4; kt++) {
            const float* xp = P.x + (size_t)row * DD + kt * 32 + quad * 8;
            float4 v0 = *(const float4*)xp;
            float4 v1 = *(const float4*)(xp + 4);
            a[kt].us[0] = f2bf(v0.x); a[kt].us[1] = f2bf(v0.y);
            a[kt].us[2] = f2bf(v0.z); a[kt].us[3] = f2bf(v0.w);
            a[kt].us[4] = f2bf(v1.x); a[kt].us[5] = f2bf(v1.y);
            a[kt].us[6] = f2bf(v1.z); a[kt].us[7] = f2bf(v1.w);
        }
        float4 dv = *(const float4*)(P.dinv + strip * 16 + quad * 4);
        float dvr[4] = {dv.x, dv.y, dv.z, dv.w};
        #pragma unroll
        for (int nt = 0; nt < 8; nt++) {
            f32x4 acc = {0.f, 0.f, 0.f, 0.f};
            #pragma unroll
            for (int kt = 0; kt < 4; kt++) {
                BF8 b;
                b.u4 = ((const uint4*)Wf0)[(nt * 4 + kt) * 64 + lane];
                acc = __builtin_amdgcn_mfma_f32_16x16x32_bf16(a[kt].v, b.v, acc, 0, 0, 0);
            }
            int colg = nt * 16 + m;
            #pragma unroll
            for (int r = 0; r < 4; r++)
                P.bufA[(size_t)(strip * 16 + quad * 4 + r) * DD + colg] = f2bf(acc[r] * dvr[r]);
        }
    }
    grid.sync();

    // ---- P5: aggregation stage 1 ----
    agg_phase((const uint*)P.bufA, (uint*)P.bufB, P.row_ptr, P.csr, P.dinv, P.b0,
              ps0, pq0, smemraw, t, bid);
    grid.sync();

    // ---- P6: GEMM2 (norm folded) ----
    {
        float* smul = (float*)smemraw;
        float* sadd = smul + 128;
        norm_params(ps0, pq0, P.gn0w, P.gn0b, P.gn0a, smul, sadd, t);
        const uint* Xp = (const uint*)P.bufB;
        for (int vb = bid; vb < GBV; vb += GRID) {
            int strip = vb * 4 + wid;
            if (strip >= NSTRIP) continue;
            int row = strip * 16 + m;
            BF8 a[4];
            #pragma unroll
            for (int kt = 0; kt < 4; kt++) {
                int f = kt * 32 + quad * 8;
                uint4 xu = *(const uint4*)(Xp + (size_t)row * 64 + kt * 16 + quad * 4);
                float4 m0 = *(const float4*)(smul + f);
                float4 m1 = *(const float4*)(smul + f + 4);
                float4 a0 = *(const float4*)(sadd + f);
                float4 a1 = *(const float4*)(sadd + f + 4);
                uint xs[4] = {xu.x, xu.y, xu.z, xu.w};
                float mm[8] = {m0.x, m0.y, m0.z, m0.w, m1.x, m1.y, m1.z, m1.w};
                float aa[8] = {a0.x, a0.y, a0.z, a0.w, a1.x, a1.y, a1.z, a1.w};
                #pragma unroll
                for (int pp = 0; pp < 4; pp++) {
                    float lo = bflo(xs[pp]), hi = bfhi(xs[pp]);
                    a[kt].us[2 * pp]     = f2bf(fmaxf(0.f, fmaf(lo, mm[2 * pp],     aa[2 * pp])));
                    a[kt].us[2 * pp + 1] = f2bf(fmaxf(0.f, fmaf(hi, mm[2 * pp + 1], aa[2 * pp + 1])));
                }
            }
            float4 dv = *(const float4*)(P.dinv + strip * 16 + quad * 4);
            float dvr[4] = {dv.x, dv.y, dv.z, dv.w};
            #pragma unroll
            for (int nt = 0; nt < 8; nt++) {
                f32x4 acc = {0.f, 0.f, 0.f, 0.f};
                #pragma unroll
                for (int kt = 0; kt < 4; kt++) {
                    BF8 b;
                    b.u4 = ((const uint4*)Wf1)[(nt * 4 + kt) * 64 + lane];
                    acc = __builtin_amdgcn_mfma_f32_16x16x32_bf16(a[kt].v, b.v, acc, 0, 0, 0);
                }
                int colg = nt * 16 + m;
                #pragma unroll
                for (int r = 0; r < 4; r++)
                    P.bufA[(size_t)(strip * 16 + quad * 4 + r) * DD + colg] = f2bf(acc[r] * dvr[r]);
            }
        }
    }
    grid.sync();

    // ---- P7: aggregation stage 2 ----
    agg_phase((const uint*)P.bufA, (uint*)P.bufB, P.row_ptr, P.csr, P.dinv, P.b1,
              ps1, pq1, smemraw, t, bid);
    grid.sync();

    // ---- P8: fused MLP head (norm folded) ----
    {
        float* smul = (float*)smemraw;
        float* sadd = smul + 128;
        norm_params(ps1, pq1, P.gn1w, P.gn1b, P.gn1a, smul, sadd, t);
        const uint* Xp = (const uint*)P.bufB;
        for (int vb = bid; vb < GBV; vb += GRID) {
            int strip = vb * 4 + wid;
            if (strip >= NSTRIP) continue;
            int row = strip * 16 + m;
            BF8 a[4];
            #pragma unroll
            for (int kt = 0; kt < 4; kt++) {
                int f = kt * 32 + quad * 8;
                uint4 xu = *(const uint4*)(Xp + (size_t)row * 64 + kt * 16 + quad * 4);
                float4 m0 = *(const float4*)(smul + f);
                float4 m1 = *(const float4*)(smul + f + 4);
                float4 a0 = *(const float4*)(sadd + f);
                float4 a1 = *(const float4*)(sadd + f + 4);
                uint xs[4] = {xu.x, xu.y, xu.z, xu.w};
                float mm[8] = {m0.x, m0.y, m0.z, m0.w, m1.x, m1.y, m1.z, m1.w};
                float aa[8] = {a0.x, a0.y, a0.z, a0.w, a1.x, a1.y, a1.z, a1.w};
                #pragma unroll
                for (int pp = 0; pp < 4; pp++) {
                    float lo = bflo(xs[pp]), hi = bfhi(xs[pp]);
                    a[kt].us[2 * pp]     = f2bf(fmaxf(0.f, fmaf(lo, mm[2 * pp],     aa[2 * pp])));
                    a[kt].us[2 * pp + 1] = f2bf(fmaxf(0.f, fmaf(hi, mm[2 * pp + 1], aa[2 * pp + 1])));
                }
            }
            float part[4] = {0.f, 0.f, 0.f, 0.f};
            #pragma unroll
            for (int nt = 0; nt < 8; nt++) {
                f32x4 acc = {0.f, 0.f, 0.f, 0.f};
                #pragma unroll
                for (int kt = 0; kt < 4; kt++) {
                    BF8 b;
                    b.u4 = ((const uint4*)Wf2)[(nt * 4 + kt) * 64 + lane];
                    acc = __builtin_amdgcn_mfma_f32_16x16x32_bf16(a[kt].v, b.v, acc, 0, 0, 0);
                }
                int colg = nt * 16 + m;
                float bb = P.lin0b[colg];
                float vv = P.lin1w[colg];
                #pragma unroll
                for (int r = 0; r < 4; r++)
                    part[r] = fmaf(fmaxf(0.f, acc[r] + bb), vv, part[r]);
            }
            #pragma unroll
            for (int r = 0; r < 4; r++) {
                #pragma unroll
                for (int off = 1; off < 16; off <<= 1)
                    part[r] += __shfl_xor(part[r], off, 64);
            }
            if (m == 0) {
                float ob = P.lin1b[0];
                #pragma unroll
                for (int r = 0; r < 4; r++)
                    P.out[strip * 16 + quad * 4 + r] = part[r] + ob;
            }
        }
    }
}

// ---------------- launch ----------------
static inline char* wsalloc(char*& p, size_t bytes) {
    char* r = p;
    p += (bytes + 255) & ~(size_t)255;
    return r;
}

extern "C" void kernel_launch(void* const* d_in, const int* in_sizes, int n_in,
                              void* d_out, int out_size, void* d_ws, size_t ws_size,
                              hipStream_t stream) {
    const float* x     = (const float*)d_in[0];
    const int*   erow  = (const int*)d_in[1];
    const int*   ecol  = ((const int*)d_in[1]) + NE;
    const float* W0    = (const float*)d_in[2];
    const float* b0    = (const float*)d_in[3];
    const float* W1    = (const float*)d_in[4];
    const float* b1    = (const float*)d_in[5];
    const float* gn0w  = (const float*)d_in[6];
    const float* gn0b  = (const float*)d_in[7];
    const float* gn0a  = (const float*)d_in[8];
    const float* gn1w  = (const float*)d_in[9];
    const float* gn1b  = (const float*)d_in[10];
    const float* gn1a  = (const float*)d_in[11];
    const float* lin0w = (const float*)d_in[12];
    const float* lin0b = (const float*)d_in[13];
    const float* lin1w = (const float*)d_in[14];
    const float* lin1b = (const float*)d_in[15];
    float* out = (float*)d_out;

    char* p = (char*)d_ws;
    ushort* bufA   = (ushort*)wsalloc(p, (size_t)NN * DD * 2);
    ushort* bufB   = (ushort*)wsalloc(p, (size_t)NN * DD * 2);
    int*    csr    = (int*)   wsalloc(p, (size_t)NE * 4);
    uint*   ebuf   = (uint*)  wsalloc(p, (size_t)NE * 4);
    int*    blk_off= (int*)   wsalloc(p, (size_t)NHB * 256 * 4);
    int*    bucket_cnt = (int*)wsalloc(p, 256 * 4);
    int*    bucket_base= (int*)wsalloc(p, 257 * 4);
    int*    row_ptr= (int*)   wsalloc(p, (size_t)(NN + 1) * 4);
    float*  dinv   = (float*) wsalloc(p, (size_t)NN * 4);
    float*  statsG = (float*) wsalloc(p, STATS_F * 4);
    ushort* Wf     = (ushort*)wsalloc(p, 3 * 2048 * 8 * 2);

    MegaP Pm;
    Pm.x = x; Pm.row = erow; Pm.col = ecol;
    Pm.b0 = b0; Pm.b1 = b1;
    Pm.gn0w = gn0w; Pm.gn0b = gn0b; Pm.gn0a = gn0a;
    Pm.gn1w = gn1w; Pm.gn1b = gn1b; Pm.gn1a = gn1a;
    Pm.lin0b = lin0b; Pm.lin1w = lin1w; Pm.lin1b = lin1b;
    Pm.W0 = W0; Pm.W1 = W1; Pm.lin0w = lin0w;
    Pm.out = out;
    Pm.bufA = bufA; Pm.bufB = bufB;
    Pm.csr = csr; Pm.ebuf = ebuf; Pm.blk_off = blk_off;
    Pm.bucket_cnt = bucket_cnt; Pm.bucket_base = bucket_base;
    Pm.row_ptr = row_ptr; Pm.dinv = dinv; Pm.statsG = statsG; Pm.Wf = Wf;

    void* kargs[] = { &Pm };
    hipError_t err = hipLaunchCooperativeKernel((const void*)k_mega, dim3(GRID),
                                                dim3(TPB), kargs, 0, stream);

    if (err != hipSuccess) {
        // ---- fallback: proven R8 9-dispatch path ----
        k_prepw3<<<24, 256, 0, stream>>>(W0, W1, lin0w, Wf, bucket_cnt, statsG);
        ushort* Wf0 = Wf;
        ushort* Wf1 = Wf + 2048 * 8;
        ushort* Wf2 = Wf + 2 * 2048 * 8;

        kb_hist <<<NHB, 256, 0, stream>>>(ecol, bucket_cnt, blk_off);
        kb_place<<<NHB, 256, 0, stream>>>(erow, ecol, bucket_cnt, blk_off, bucket_base, ebuf);
        kb_fin  <<<NBUCK, 512, 0, stream>>>(ebuf, bucket_base, row_ptr, dinv, csr);

        const int GB = (NSTRIP + 3) / 4;
        float* ps0 = statsG;
        float* pq0 = statsG + NSHARD * 128;
        float* ps1 = statsG + 2 * NSHARD * 128;
        float* pq1 = statsG + 3 * NSHARD * 128;

        k_gemmA<<<GB, 256, 0, stream>>>(x, Wf0, dinv, bufA);
        k_agg2 <<<NN / 8, 512, 0, stream>>>((const uint*)bufA, row_ptr, csr, dinv, b0,
                                            (uint*)bufB, ps0, pq0);
        k_gemmB<<<GB, 256, 0, stream>>>((const uint*)bufB, Wf1, ps0, pq0,
                                        gn0w, gn0b, gn0a, dinv, bufA);
        k_agg2 <<<NN / 8, 512, 0, stream>>>((const uint*)bufA, row_ptr, csr, dinv, b1,
                                            (uint*)bufB, ps1, pq1);
        k_mlp<<<GB, 256, 0, stream>>>((const uint*)bufB, Wf2, ps1, pq1,
                                      gn1w, gn1b, gn1a,
                                      lin0b, lin1w, lin1b, out);
    }

    (void)in_sizes; (void)n_in; (void)out_size; (void)ws_size;
}

// Round 11
// 411.130 us; speedup vs baseline: 2.8437x; 2.8437x over previous
//
#include <hip/hip_runtime.h>

// ---------------- problem constants ----------------
#define NN 100000      // nodes
#define NE 1600000     // edges (without self loops)
#define DD 128         // feature dim
#define EPSV 1e-5f

#define NSTRIP 6250            // NN/16 row-strips for MFMA gemms

// bucket sort: 196 buckets of 512 nodes; 782 hist/place blocks of 2048 edges
#define BSHIFT 9
#define NBUCK 196
#define EPB 2048
#define NHB 782

#define NSHARD 32              // stats atomic shards
#define STATS_F (4 * NSHARD * 128)   // 2 stages x (sum|sq)[32][128]

typedef __attribute__((ext_vector_type(8))) __bf16 bf16x8;
typedef __attribute__((ext_vector_type(4))) float f32x4;

union BF8 {                // bit-level construction of MFMA bf16 fragments
    ushort  us[8];
    uint    ui[4];
    uint4   u4;
    bf16x8  v;
};

__device__ __forceinline__ ushort f2bf(float f) {   // RNE fp32 -> bf16 bits
    uint u = __float_as_uint(f);
    return (ushort)((u + 0x7fffu + ((u >> 16) & 1u)) >> 16);
}
__device__ __forceinline__ float bflo(uint u) { return __uint_as_float(u << 16); }
__device__ __forceinline__ float bfhi(uint u) { return __uint_as_float(u & 0xffff0000u); }

// ------ weight prep (runs FIRST): 3x W[128x128] fp32 -> B-frag bf16 + zero scratch ------
__global__ void k_prepw3(const float* __restrict__ WA, const float* __restrict__ WB,
                         const float* __restrict__ WC, ushort* __restrict__ Wf,
                         int* __restrict__ bucket_cnt, float* __restrict__ statsG,
                         int* __restrict__ deg) {
    int gid = blockIdx.x * 256 + threadIdx.x;        // 0..6143
    if (gid < 256) bucket_cnt[gid] = 0;
    for (int i = gid; i < STATS_F; i += 24 * 256) statsG[i] = 0.f;
    for (int i = gid; i < NN; i += 24 * 256) deg[i] = 0;

    int which = blockIdx.x >> 3;
    const float* W = (which == 0) ? WA : ((which == 1) ? WB : WC);
    int t = (blockIdx.x & 7) * 256 + threadIdx.x;    // 0..2047
    int lane = t & 63;
    int kt = (t >> 6) & 3;
    int nt = t >> 8;
    int quad = lane >> 4;
    int n = nt * 16 + (lane & 15);
    BF8 f;
    #pragma unroll
    for (int j = 0; j < 8; j++)
        f.us[j] = f2bf(W[(kt * 32 + quad * 8 + j) * DD + n]);
    ((uint4*)(Wf + (size_t)which * 2048 * 8))[t] = f.u4;
}

// ---- bucket histogram + per-node degree (global atomics; R7 proved deg atomics cheap) ----
__global__ __launch_bounds__(256)
void kb_hist(const int* __restrict__ col, int* __restrict__ bucket_cnt,
             int* __restrict__ blk_off, int* __restrict__ deg) {
    __shared__ int h[256];
    int t = threadIdx.x;
    h[t] = 0;
    __syncthreads();
    int e0 = blockIdx.x * EPB;
    #pragma unroll
    for (int j = 0; j < 8; j++) {
        int e = e0 + t + j * 256;
        if (e < NE) {
            int c = col[e];
            atomicAdd(&h[c >> BSHIFT], 1);
            atomicAdd(&deg[c], 1);
        }
    }
    __syncthreads();
    int c = h[t];
    blk_off[blockIdx.x * 256 + t] = c ? atomicAdd(&bucket_cnt[t], c) : 0;
}

// ---- FUSED place + GEMM1: blocks<NHB place edges; all 1563 blocks run gemmA with
//      dinv computed inline from deg (bit-identical to kb_fin's rsqrt(d+1)) ----
__global__ __launch_bounds__(256)
void kb_placeA(const int* __restrict__ row, const int* __restrict__ col,
               const int* __restrict__ bucket_cnt, const int* __restrict__ blk_off,
               int* __restrict__ bucket_base, uint* __restrict__ ebuf,
               const float* __restrict__ X, const ushort* __restrict__ Wf,
               const int* __restrict__ deg, ushort* __restrict__ Y) {
    const int t = threadIdx.x;
    const int bid = blockIdx.x;

    if (bid < NHB) {                       // block-uniform branch: place pass
        __shared__ int s[256];
        __shared__ int cur[256];
        int v = bucket_cnt[t];
        s[t] = v;
        __syncthreads();
        for (int off = 1; off < 256; off <<= 1) {
            int u = (t >= off) ? s[t - off] : 0;
            __syncthreads();
            s[t] += u;
            __syncthreads();
        }
        int base = s[t] - v;               // exclusive prefix
        cur[t] = base + blk_off[bid * 256 + t];
        if (bid == 0) {
            bucket_base[t] = base;
            if (t == 255) bucket_base[256] = s[255];
        }
        __syncthreads();
        int e0 = bid * EPB;
        #pragma unroll
        for (int j = 0; j < 8; j++) {
            int e = e0 + t + j * 256;
            if (e < NE) {
                int c = col[e];
                int pos = atomicAdd(&cur[c >> BSHIFT], 1);
                ebuf[pos] = ((uint)row[e] << BSHIFT) | (uint)(c & ((1 << BSHIFT) - 1));
            }
        }
    }

    // ---- gemmA part (no dependence on place/fin: dinv from deg inline) ----
    int strip = bid * 4 + (t >> 6);
    if (strip < NSTRIP) {
        int lane = t & 63;
        int quad = lane >> 4;
        int m = lane & 15;
        int rowi = strip * 16 + m;

        BF8 a[4];
        #pragma unroll
        for (int kt = 0; kt < 4; kt++) {
            const float* xp = X + (size_t)rowi * DD + kt * 32 + quad * 8;
            float4 v0 = *(const float4*)xp;
            float4 v1 = *(const float4*)(xp + 4);
            a[kt].us[0] = f2bf(v0.x); a[kt].us[1] = f2bf(v0.y);
            a[kt].us[2] = f2bf(v0.z); a[kt].us[3] = f2bf(v0.w);
            a[kt].us[4] = f2bf(v1.x); a[kt].us[5] = f2bf(v1.y);
            a[kt].us[6] = f2bf(v1.z); a[kt].us[7] = f2bf(v1.w);
        }

        int4 dg = *(const int4*)(deg + strip * 16 + quad * 4);
        float dvr[4] = { rsqrtf((float)(dg.x + 1)), rsqrtf((float)(dg.y + 1)),
                         rsqrtf((float)(dg.z + 1)), rsqrtf((float)(dg.w + 1)) };

        #pragma unroll
        for (int nt = 0; nt < 8; nt++) {
            f32x4 acc = {0.f, 0.f, 0.f, 0.f};
            #pragma unroll
            for (int kt = 0; kt < 4; kt++) {
                BF8 b;
                b.u4 = ((const uint4*)Wf)[(nt * 4 + kt) * 64 + lane];
                acc = __builtin_amdgcn_mfma_f32_16x16x32_bf16(a[kt].v, b.v, acc, 0, 0, 0);
            }
            int colg = nt * 16 + m;
            #pragma unroll
            for (int r = 0; r < 4; r++)
                Y[(size_t)(strip * 16 + quad * 4 + r) * DD + colg] = f2bf(acc[r] * dvr[r]);
        }
    }
}

// per-bucket finalize at 512 threads (R8-proven)
__global__ __launch_bounds__(512)
void kb_fin(const uint* __restrict__ ebuf, const int* __restrict__ bucket_base,
            int* __restrict__ row_ptr, float* __restrict__ dinv,
            int* __restrict__ csr) {
    __shared__ int deg[512];
    __shared__ int scn[512];
    int b = blockIdx.x;
    int n0 = b << BSHIFT;
    int t = threadIdx.x;
    deg[t] = 0;
    __syncthreads();
    int s = bucket_base[b], e = bucket_base[b + 1];
    for (int p = s + t; p < e; p += 512)
        atomicAdd(&deg[ebuf[p] & 511u], 1);
    __syncthreads();
    int d = deg[t];
    scn[t] = d;
    __syncthreads();
    for (int off = 1; off < 512; off <<= 1) {
        int u = (t >= off) ? scn[t - off] : 0;
        __syncthreads();
        scn[t] += u;
        __syncthreads();
    }
    int base = s + scn[t] - d;
    int node = n0 + t;
    if (node < NN) { row_ptr[node] = base; dinv[node] = rsqrtf((float)(d + 1)); }
    __syncthreads();
    deg[t] = base;
    __syncthreads();
    for (int p = s + t; p < e; p += 512) {
        uint r = ebuf[p];
        int pos = atomicAdd(&deg[r & 511u], 1);
        csr[pos] = (int)(r >> BSHIFT);
    }
    if (b == 0 && t == 0) row_ptr[NN] = NE;
}

// -------- GEMM2: G = (bf16(relu(norm(X_bf16))) @ Wf) * dinv ; norm params from partials ----
__global__ __launch_bounds__(256)
void k_gemmB(const uint* __restrict__ Xp, const ushort* __restrict__ Wf,
             const float* __restrict__ psum, const float* __restrict__ psq,
             const float* __restrict__ gw, const float* __restrict__ gb,
             const float* __restrict__ ga,
             const float* __restrict__ dinv, ushort* __restrict__ Y) {
    __shared__ float smul[128], sadd[128];
    {
        int f = threadIdx.x;
        if (f < 128) {
            float s = 0.f, q = 0.f;
            #pragma unroll
            for (int sh = 0; sh < NSHARD; sh++) { s += psum[sh * 128 + f]; q += psq[sh * 128 + f]; }
            const float invn = 1.0f / (float)NN;
            float mm = s * invn, ex2 = q * invn, av = ga[f];
            float var = ex2 - mm * mm * (2.f * av - av * av);
            float inv = rsqrtf(var + EPSV);
            smul[f] = gw[f] * inv;
            sadd[f] = gb[f] - gw[f] * inv * av * mm;
        }
    }
    __syncthreads();
    int strip = blockIdx.x * 4 + (threadIdx.x >> 6);
    if (strip >= NSTRIP) return;
    int lane = threadIdx.x & 63;
    int quad = lane >> 4;
    int m = lane & 15;
    int row = strip * 16 + m;

    BF8 a[4];
    #pragma unroll
    for (int kt = 0; kt < 4; kt++) {
        int f = kt * 32 + quad * 8;
        uint4 xu = *(const uint4*)(Xp + (size_t)row * 64 + kt * 16 + quad * 4);
        float4 m0 = *(const float4*)(smul + f);
        float4 m1 = *(const float4*)(smul + f + 4);
        float4 a0 = *(const float4*)(sadd + f);
        float4 a1 = *(const float4*)(sadd + f + 4);
        uint xs[4] = {xu.x, xu.y, xu.z, xu.w};
        float mm[8] = {m0.x, m0.y, m0.z, m0.w, m1.x, m1.y, m1.z, m1.w};
        float aa[8] = {a0.x, a0.y, a0.z, a0.w, a1.x, a1.y, a1.z, a1.w};
        #pragma unroll
        for (int p = 0; p < 4; p++) {
            float lo = bflo(xs[p]), hi = bfhi(xs[p]);
            a[kt].us[2 * p]     = f2bf(fmaxf(0.f, fmaf(lo, mm[2 * p],     aa[2 * p])));
            a[kt].us[2 * p + 1] = f2bf(fmaxf(0.f, fmaf(hi, mm[2 * p + 1], aa[2 * p + 1])));
        }
    }

    float4 dv = *(const float4*)(dinv + strip * 16 + quad * 4);
    float dvr[4] = {dv.x, dv.y, dv.z, dv.w};

    #pragma unroll
    for (int nt = 0; nt < 8; nt++) {
        f32x4 acc = {0.f, 0.f, 0.f, 0.f};
        #pragma unroll
        for (int kt = 0; kt < 4; kt++) {
            BF8 b;
            b.u4 = ((const uint4*)Wf)[(nt * 4 + kt) * 64 + lane];
            acc = __builtin_amdgcn_mfma_f32_16x16x32_bf16(a[kt].v, b.v, acc, 0, 0, 0);
        }
        int colg = nt * 16 + m;
        #pragma unroll
        for (int r = 0; r < 4; r++)
            Y[(size_t)(strip * 16 + quad * 4 + r) * DD + colg] = f2bf(acc[r] * dvr[r]);
    }
}

// ---------------- aggregation: 16 waves = 16 nodes/block (6250 blocks) ----------------
// 1024 threads -> 2 blocks/CU = 32 waves/CU (vs ~23 at 512): more gather TLP.
// Stats epilogue halved: 6250 x 256 atomics.
__global__ __launch_bounds__(1024)
void k_agg2(const uint* __restrict__ H2,
            const int* __restrict__ row_ptr, const int* __restrict__ csr,
            const float* __restrict__ dinv,
            const float* __restrict__ bias, uint* __restrict__ Y2,
            float* __restrict__ psumG, float* __restrict__ psqG) {
    const int lane = threadIdx.x & 63;
    const int wid  = threadIdx.x >> 6;
    const int i = __builtin_amdgcn_readfirstlane(blockIdx.x * 16 + wid);
    const int p0 = row_ptr[i], p1 = row_ptr[i + 1];
    const float di = dinv[i];
    uint su = H2[(size_t)i * 64 + lane];
    float a0 = bflo(su), a1 = bfhi(su);            // self loop term g[i]
    float b0 = 0.f, b1 = 0.f, c0 = 0.f, c1 = 0.f, d0 = 0.f, d1 = 0.f;
    int p = p0;
    for (; p + 7 < p1; p += 8) {                   // 8 loads in flight
        int s0 = csr[p],     s1 = csr[p + 1], s2 = csr[p + 2], s3 = csr[p + 3];
        int s4 = csr[p + 4], s5 = csr[p + 5], s6 = csr[p + 6], s7 = csr[p + 7];
        uint h0 = H2[(size_t)s0 * 64 + lane];
        uint h1 = H2[(size_t)s1 * 64 + lane];
        uint h2 = H2[(size_t)s2 * 64 + lane];
        uint h3 = H2[(size_t)s3 * 64 + lane];
        uint h4 = H2[(size_t)s4 * 64 + lane];
        uint h5 = H2[(size_t)s5 * 64 + lane];
        uint h6 = H2[(size_t)s6 * 64 + lane];
        uint h7 = H2[(size_t)s7 * 64 + lane];
        a0 += bflo(h0); a1 += bfhi(h0);
        b0 += bflo(h1); b1 += bfhi(h1);
        c0 += bflo(h2); c1 += bfhi(h2);
        d0 += bflo(h3); d1 += bfhi(h3);
        a0 += bflo(h4); a1 += bfhi(h4);
        b0 += bflo(h5); b1 += bfhi(h5);
        c0 += bflo(h6); c1 += bfhi(h6);
        d0 += bflo(h7); d1 += bfhi(h7);
    }
    for (; p + 3 < p1; p += 4) {
        int s0 = csr[p], s1 = csr[p + 1], s2 = csr[p + 2], s3 = csr[p + 3];
        uint h0 = H2[(size_t)s0 * 64 + lane];
        uint h1 = H2[(size_t)s1 * 64 + lane];
        uint h2 = H2[(size_t)s2 * 64 + lane];
        uint h3 = H2[(size_t)s3 * 64 + lane];
        a0 += bflo(h0); a1 += bfhi(h0);
        b0 += bflo(h1); b1 += bfhi(h1);
        c0 += bflo(h2); c1 += bfhi(h2);
        d0 += bflo(h3); d1 += bfhi(h3);
    }
    for (; p < p1; p++) {
        uint h0 = H2[(size_t)csr[p] * 64 + lane];
        a0 += bflo(h0); a1 += bfhi(h0);
    }
    float2 bb = *(const float2*)(bias + 2 * lane);
    float r0 = fmaf((a0 + b0) + (c0 + d0), di, bb.x);
    float r1 = fmaf((a1 + b1) + (c1 + d1), di, bb.y);
    Y2[(size_t)i * 64 + lane] = (uint)f2bf(r0) | ((uint)f2bf(r1) << 16);

    // fused GraphNorm partial stats over the block's 16 nodes
    __shared__ float ls[16][128], lq[16][128];
    ls[wid][2 * lane]     = r0;      ls[wid][2 * lane + 1] = r1;
    lq[wid][2 * lane]     = r0 * r0; lq[wid][2 * lane + 1] = r1 * r1;
    __syncthreads();
    if (threadIdx.x < 128) {
        int f = threadIdx.x;
        float s = 0.f, q = 0.f;
        #pragma unroll
        for (int w = 0; w < 16; w++) { s += ls[w][f]; q += lq[w][f]; }
        int sh = (blockIdx.x & (NSHARD - 1)) * 128 + f;
        atomicAdd(&psumG[sh], s);
        atomicAdd(&psqG[sh], q);
    }
}

// ------- fused MLP head (MFMA): out = relu(T(norm(X))@W + b0h) @ v1 + b1 ; norm folded ------
__global__ __launch_bounds__(256)
void k_mlp(const uint* __restrict__ Xp, const ushort* __restrict__ Wf,
           const float* __restrict__ psum, const float* __restrict__ psq,
           const float* __restrict__ gw, const float* __restrict__ gb,
           const float* __restrict__ ga,
           const float* __restrict__ b0h, const float* __restrict__ v1,
           const float* __restrict__ b1, float* __restrict__ out) {
    __shared__ float smul[128], sadd[128];
    {
        int f = threadIdx.x;
        if (f < 128) {
            float s = 0.f, q = 0.f;
            #pragma unroll
            for (int sh = 0; sh < NSHARD; sh++) { s += psum[sh * 128 + f]; q += psq[sh * 128 + f]; }
            const float invn = 1.0f / (float)NN;
            float mm = s * invn, ex2 = q * invn, av = ga[f];
            float var = ex2 - mm * mm * (2.f * av - av * av);
            float inv = rsqrtf(var + EPSV);
            smul[f] = gw[f] * inv;
            sadd[f] = gb[f] - gw[f] * inv * av * mm;
        }
    }
    __syncthreads();
    int strip = blockIdx.x * 4 + (threadIdx.x >> 6);
    if (strip >= NSTRIP) return;
    int lane = threadIdx.x & 63;
    int quad = lane >> 4;
    int m = lane & 15;
    int row = strip * 16 + m;

    BF8 a[4];
    #pragma unroll
    for (int kt = 0; kt < 4; kt++) {
        int f = kt * 32 + quad * 8;
        uint4 xu = *(const uint4*)(Xp + (size_t)row * 64 + kt * 16 + quad * 4);
        float4 m0 = *(const float4*)(smul + f);
        float4 m1 = *(const float4*)(smul + f + 4);
        float4 a0 = *(const float4*)(sadd + f);
        float4 a1 = *(const float4*)(sadd + f + 4);
        uint xs[4] = {xu.x, xu.y, xu.z, xu.w};
        float mm[8] = {m0.x, m0.y, m0.z, m0.w, m1.x, m1.y, m1.z, m1.w};
        float aa[8] = {a0.x, a0.y, a0.z, a0.w, a1.x, a1.y, a1.z, a1.w};
        #pragma unroll
        for (int p = 0; p < 4; p++) {
            float lo = bflo(xs[p]), hi = bfhi(xs[p]);
            a[kt].us[2 * p]     = f2bf(fmaxf(0.f, fmaf(lo, mm[2 * p],     aa[2 * p])));
            a[kt].us[2 * p + 1] = f2bf(fmaxf(0.f, fmaf(hi, mm[2 * p + 1], aa[2 * p + 1])));
        }
    }

    float part[4] = {0.f, 0.f, 0.f, 0.f};
    #pragma unroll
    for (int nt = 0; nt < 8; nt++) {
        f32x4 acc = {0.f, 0.f, 0.f, 0.f};
        #pragma unroll
        for (int kt = 0; kt < 4; kt++) {
            BF8 b;
            b.u4 = ((const uint4*)Wf)[(nt * 4 + kt) * 64 + lane];
            acc = __builtin_amdgcn_mfma_f32_16x16x32_bf16(a[kt].v, b.v, acc, 0, 0, 0);
        }
        int colg = nt * 16 + m;
        float bb = b0h[colg];
        float vv = v1[colg];
        #pragma unroll
        for (int r = 0; r < 4; r++)
            part[r] = fmaf(fmaxf(0.f, acc[r] + bb), vv, part[r]);
    }
    #pragma unroll
    for (int r = 0; r < 4; r++) {
        #pragma unroll
        for (int off = 1; off < 16; off <<= 1)
            part[r] += __shfl_xor(part[r], off, 64);
    }
    if (m == 0) {
        float ob = b1[0];
        #pragma unroll
        for (int r = 0; r < 4; r++)
            out[strip * 16 + quad * 4 + r] = part[r] + ob;
    }
}

// ---------------- launch ----------------
static inline char* wsalloc(char*& p, size_t bytes) {
    char* r = p;
    p += (bytes + 255) & ~(size_t)255;
    return r;
}

extern "C" void kernel_launch(void* const* d_in, const int* in_sizes, int n_in,
                              void* d_out, int out_size, void* d_ws, size_t ws_size,
                              hipStream_t stream) {
    const float* x     = (const float*)d_in[0];
    const int*   ei    = (const int*)d_in[1];
    const int*   erow  = ei;
    const int*   ecol  = ei + NE;
    const float* W0    = (const float*)d_in[2];
    const float* b0    = (const float*)d_in[3];
    const float* W1    = (const float*)d_in[4];
    const float* b1    = (const float*)d_in[5];
    const float* gn0w  = (const float*)d_in[6];
    const float* gn0b  = (const float*)d_in[7];
    const float* gn0a  = (const float*)d_in[8];
    const float* gn1w  = (const float*)d_in[9];
    const float* gn1b  = (const float*)d_in[10];
    const float* gn1a  = (const float*)d_in[11];
    const float* lin0w = (const float*)d_in[12];
    const float* lin0b = (const float*)d_in[13];
    const float* lin1w = (const float*)d_in[14];
    const float* lin1b = (const float*)d_in[15];
    float* out = (float*)d_out;

    char* p = (char*)d_ws;
    ushort* bufA   = (ushort*)wsalloc(p, (size_t)NN * DD * 2);   // bf16 g = h*dinv
    ushort* bufB   = (ushort*)wsalloc(p, (size_t)NN * DD * 2);   // bf16 agg out
    int*    csr    = (int*)   wsalloc(p, (size_t)NE * 4);        // src only
    uint*   ebuf   = (uint*)  wsalloc(p, (size_t)NE * 4);        // packed (src<<9)|local
    int*    blk_off= (int*)   wsalloc(p, (size_t)NHB * 256 * 4);
    int*    bucket_cnt = (int*)wsalloc(p, 256 * 4);
    int*    bucket_base= (int*)wsalloc(p, 257 * 4);
    int*    row_ptr= (int*)   wsalloc(p, (size_t)(NN + 1) * 4);
    float*  dinv   = (float*) wsalloc(p, (size_t)NN * 4);
    int*    deg    = (int*)   wsalloc(p, (size_t)NN * 4);
    float*  statsG = (float*) wsalloc(p, STATS_F * 4);
    ushort* Wf     = (ushort*)wsalloc(p, 3 * 2048 * 8 * 2);      // 3 prepped weights

    // 1) weight prep + zero scratch (bucket_cnt, statsG, deg)
    k_prepw3<<<24, 256, 0, stream>>>(W0, W1, lin0w, Wf, bucket_cnt, statsG, deg);
    ushort* Wf0 = Wf;
    ushort* Wf1 = Wf + 2048 * 8;
    ushort* Wf2 = Wf + 2 * 2048 * 8;

    // 2) bucket histogram + per-node degrees
    kb_hist<<<NHB, 256, 0, stream>>>(ecol, bucket_cnt, blk_off, deg);

    const int GB = (NSTRIP + 3) / 4;   // 1563 blocks

    // 3) FUSED: edge placement (blocks<782) + gemmA with inline dinv (all blocks)
    kb_placeA<<<GB, 256, 0, stream>>>(erow, ecol, bucket_cnt, blk_off, bucket_base,
                                      ebuf, x, Wf0, deg, bufA);

    // 4) per-bucket finalize (row_ptr / dinv / csr)
    kb_fin<<<NBUCK, 512, 0, stream>>>(ebuf, bucket_base, row_ptr, dinv, csr);

    float* ps0 = statsG;
    float* pq0 = statsG + NSHARD * 128;
    float* ps1 = statsG + 2 * NSHARD * 128;
    float* pq1 = statsG + 3 * NSHARD * 128;

    // 5) aggregation stage 1 (16 nodes/block)
    k_agg2<<<NN / 16, 1024, 0, stream>>>((const uint*)bufA, row_ptr, csr, dinv, b0,
                                         (uint*)bufB, ps0, pq0);

    // 6) GEMM2 (GraphNorm params folded into prologue)
    k_gemmB<<<GB, 256, 0, stream>>>((const uint*)bufB, Wf1, ps0, pq0,
                                    gn0w, gn0b, gn0a, dinv, bufA);

    // 7) aggregation stage 2
    k_agg2<<<NN / 16, 1024, 0, stream>>>((const uint*)bufA, row_ptr, csr, dinv, b1,
                                         (uint*)bufB, ps1, pq1);

    // 8) fused MLP head (GraphNorm params folded into prologue)
    k_mlp<<<GB, 256, 0, stream>>>((const uint*)bufB, Wf2, ps1, pq1,
                                  gn1w, gn1b, gn1a,
                                  lin0b, lin1w, lin1b, out);

    (void)in_sizes; (void)n_in; (void)out_size; (void)ws_size;
}

// Round 12
// 338.070 us; speedup vs baseline: 3.4582x; 1.2161x over previous
//
#include <hip/hip_runtime.h>

// ---------------- problem constants ----------------
#define NN 100000      // nodes
#define NE 1600000     // edges (without self loops)
#define DD 128         // feature dim
#define EPSV 1e-5f

#define NSTRIP 6250            // NN/16 row-strips for MFMA gemms

// bucket sort: 196 buckets of 512 nodes; 782 histplace blocks of 2048 edges
#define BSHIFT 9
#define NBUCK 196
#define EPB 2048
#define NHB 782
#define CAP 12288              // fixed bucket capacity (mean 8163, sd~90: 45 sigma)

#define NSHARD 32              // stats atomic shards
#define STATS_F (4 * NSHARD * 128)   // 2 stages x (sum|sq)[32][128]

typedef __attribute__((ext_vector_type(8))) __bf16 bf16x8;
typedef __attribute__((ext_vector_type(4))) float f32x4;

union BF8 {                // bit-level construction of MFMA bf16 fragments
    ushort  us[8];
    uint    ui[4];
    uint4   u4;
    bf16x8  v;
};

__device__ __forceinline__ ushort f2bf(float f) {   // RNE fp32 -> bf16 bits
    uint u = __float_as_uint(f);
    return (ushort)((u + 0x7fffu + ((u >> 16) & 1u)) >> 16);
}
__device__ __forceinline__ float bflo(uint u) { return __uint_as_float(u << 16); }
__device__ __forceinline__ float bfhi(uint u) { return __uint_as_float(u & 0xffff0000u); }

// ------ weight prep (runs FIRST): 3x W[128x128] fp32 -> B-frag bf16 + zero scratch ------
__global__ void k_prepw3(const float* __restrict__ WA, const float* __restrict__ WB,
                         const float* __restrict__ WC, ushort* __restrict__ Wf,
                         int* __restrict__ cnt, float* __restrict__ statsG) {
    int gid = blockIdx.x * 256 + threadIdx.x;        // 0..6143
    if (gid < 256) cnt[gid] = 0;
    for (int i = gid; i < STATS_F; i += 24 * 256) statsG[i] = 0.f;

    int which = blockIdx.x >> 3;
    const float* W = (which == 0) ? WA : ((which == 1) ? WB : WC);
    int t = (blockIdx.x & 7) * 256 + threadIdx.x;    // 0..2047
    int lane = t & 63;
    int kt = (t >> 6) & 3;
    int nt = t >> 8;
    int quad = lane >> 4;
    int n = nt * 16 + (lane & 15);
    BF8 f;
    #pragma unroll
    for (int j = 0; j < 8; j++)
        f.us[j] = f2bf(W[(kt * 32 + quad * 8 + j) * DD + n]);
    ((uint4*)(Wf + (size_t)which * 2048 * 8))[t] = f.u4;
}

// ---- FUSED hist+place: LDS hist -> one global atomic per bucket (reservation) ->
//      place into fixed-capacity bucket slot. No global scan, no blk_off. ----
__global__ __launch_bounds__(256)
void kb_histplace(const int* __restrict__ row, const int* __restrict__ col,
                  int* __restrict__ cnt, uint* __restrict__ ebuf) {
    __shared__ int h[256];
    __shared__ int curl[256];      // per-bucket local cursor (offset within bucket)
    int t = threadIdx.x;
    h[t] = 0;
    __syncthreads();
    int e0 = blockIdx.x * EPB;
    #pragma unroll
    for (int j = 0; j < 8; j++) {
        int e = e0 + t + j * 256;
        if (e < NE) atomicAdd(&h[col[e] >> BSHIFT], 1);
    }
    __syncthreads();
    int c = h[t];
    curl[t] = c ? atomicAdd(&cnt[t], c) : 0;   // block's reservation in bucket t
    __syncthreads();
    #pragma unroll
    for (int j = 0; j < 8; j++) {
        int e = e0 + t + j * 256;
        if (e < NE) {
            int cc = col[e];
            int b = cc >> BSHIFT;
            int pl = atomicAdd(&curl[b], 1);
            if (pl < CAP)                      // 45-sigma guard; no drops in practice
                ebuf[(size_t)b * CAP + pl] = ((uint)row[e] << BSHIFT) | (uint)(cc & 511);
        }
    }
}

// per-bucket finalize: global base from 196-prefix of cnt; row_ptr/dinv/csr as R8
__global__ __launch_bounds__(512)
void kb_fin(const uint* __restrict__ ebuf, const int* __restrict__ cnt,
            int* __restrict__ row_ptr, float* __restrict__ dinv,
            int* __restrict__ csr) {
    __shared__ int deg[512];
    __shared__ int scn[512];
    __shared__ int red[512];
    const int b = blockIdx.x;
    const int t = threadIdx.x;
    // s = sum cnt[0..b) (b<=195 so at most one element per thread)
    red[t] = (t < b) ? cnt[t] : 0;
    __syncthreads();
    #pragma unroll
    for (int off = 256; off > 0; off >>= 1) {
        if (t < off) red[t] += red[t + off];
        __syncthreads();
    }
    const int s = red[0];
    int e = cnt[b]; if (e > CAP) e = CAP;
    const uint* eb = ebuf + (size_t)b * CAP;

    deg[t] = 0;
    __syncthreads();
    for (int p = t; p < e; p += 512)
        atomicAdd(&deg[eb[p] & 511u], 1);
    __syncthreads();
    int d = deg[t];
    scn[t] = d;
    __syncthreads();
    for (int off = 1; off < 512; off <<= 1) {
        int u = (t >= off) ? scn[t - off] : 0;
        __syncthreads();
        scn[t] += u;
        __syncthreads();
    }
    int base = s + scn[t] - d;                 // global CSR offset of node n0+t
    int node = (b << BSHIFT) + t;
    if (node < NN) { row_ptr[node] = base; dinv[node] = rsqrtf((float)(d + 1)); }
    __syncthreads();                           // before reusing deg[] as cursors
    deg[t] = base;
    __syncthreads();
    for (int p = t; p < e; p += 512) {
        uint r = eb[p];
        int pos = atomicAdd(&deg[r & 511u], 1);
        csr[pos] = (int)(r >> BSHIFT);         // 4B record: src only
    }
    if (b == 0 && t == 0) row_ptr[NN] = NE;
}

// ---------------- GEMM1: G_bf16[N,128] = (bf16(X_f32) @ Wf) * dinv[row] ----------------
__global__ __launch_bounds__(256)
void k_gemmA(const float* __restrict__ X, const ushort* __restrict__ Wf,
             const float* __restrict__ dinv, ushort* __restrict__ Y) {
    int strip = blockIdx.x * 4 + (threadIdx.x >> 6);
    if (strip >= NSTRIP) return;
    int lane = threadIdx.x & 63;
    int quad = lane >> 4;
    int m = lane & 15;
    int row = strip * 16 + m;

    BF8 a[4];
    #pragma unroll
    for (int kt = 0; kt < 4; kt++) {
        const float* xp = X + (size_t)row * DD + kt * 32 + quad * 8;
        float4 v0 = *(const float4*)xp;
        float4 v1 = *(const float4*)(xp + 4);
        a[kt].us[0] = f2bf(v0.x); a[kt].us[1] = f2bf(v0.y);
        a[kt].us[2] = f2bf(v0.z); a[kt].us[3] = f2bf(v0.w);
        a[kt].us[4] = f2bf(v1.x); a[kt].us[5] = f2bf(v1.y);
        a[kt].us[6] = f2bf(v1.z); a[kt].us[7] = f2bf(v1.w);
    }

    float4 dv = *(const float4*)(dinv + strip * 16 + quad * 4);
    float dvr[4] = {dv.x, dv.y, dv.z, dv.w};

    #pragma unroll
    for (int nt = 0; nt < 8; nt++) {
        f32x4 acc = {0.f, 0.f, 0.f, 0.f};
        #pragma unroll
        for (int kt = 0; kt < 4; kt++) {
            BF8 b;
            b.u4 = ((const uint4*)Wf)[(nt * 4 + kt) * 64 + lane];
            acc = __builtin_amdgcn_mfma_f32_16x16x32_bf16(a[kt].v, b.v, acc, 0, 0, 0);
        }
        int colg = nt * 16 + m;
        #pragma unroll
        for (int r = 0; r < 4; r++)
            Y[(size_t)(strip * 16 + quad * 4 + r) * DD + colg] = f2bf(acc[r] * dvr[r]);
    }
}

// -------- GEMM2: G = (bf16(relu(norm(X_bf16))) @ Wf) * dinv ; norm params from partials ----
__global__ __launch_bounds__(256)
void k_gemmB(const uint* __restrict__ Xp, const ushort* __restrict__ Wf,
             const float* __restrict__ psum, const float* __restrict__ psq,
             const float* __restrict__ gw, const float* __restrict__ gb,
             const float* __restrict__ ga,
             const float* __restrict__ dinv, ushort* __restrict__ Y) {
    __shared__ float smul[128], sadd[128];
    {
        int f = threadIdx.x;
        if (f < 128) {
            float s = 0.f, q = 0.f;
            #pragma unroll
            for (int sh = 0; sh < NSHARD; sh++) { s += psum[sh * 128 + f]; q += psq[sh * 128 + f]; }
            const float invn = 1.0f / (float)NN;
            float mm = s * invn, ex2 = q * invn, av = ga[f];
            float var = ex2 - mm * mm * (2.f * av - av * av);
            float inv = rsqrtf(var + EPSV);
            smul[f] = gw[f] * inv;
            sadd[f] = gb[f] - gw[f] * inv * av * mm;
        }
    }
    __syncthreads();
    int strip = blockIdx.x * 4 + (threadIdx.x >> 6);
    if (strip >= NSTRIP) return;
    int lane = threadIdx.x & 63;
    int quad = lane >> 4;
    int m = lane & 15;
    int row = strip * 16 + m;

    BF8 a[4];
    #pragma unroll
    for (int kt = 0; kt < 4; kt++) {
        int f = kt * 32 + quad * 8;
        uint4 xu = *(const uint4*)(Xp + (size_t)row * 64 + kt * 16 + quad * 4);
        float4 m0 = *(const float4*)(smul + f);
        float4 m1 = *(const float4*)(smul + f + 4);
        float4 a0 = *(const float4*)(sadd + f);
        float4 a1 = *(const float4*)(sadd + f + 4);
        uint xs[4] = {xu.x, xu.y, xu.z, xu.w};
        float mm[8] = {m0.x, m0.y, m0.z, m0.w, m1.x, m1.y, m1.z, m1.w};
        float aa[8] = {a0.x, a0.y, a0.z, a0.w, a1.x, a1.y, a1.z, a1.w};
        #pragma unroll
        for (int p = 0; p < 4; p++) {
            float lo = bflo(xs[p]), hi = bfhi(xs[p]);
            a[kt].us[2 * p]     = f2bf(fmaxf(0.f, fmaf(lo, mm[2 * p],     aa[2 * p])));
            a[kt].us[2 * p + 1] = f2bf(fmaxf(0.f, fmaf(hi, mm[2 * p + 1], aa[2 * p + 1])));
        }
    }

    float4 dv = *(const float4*)(dinv + strip * 16 + quad * 4);
    float dvr[4] = {dv.x, dv.y, dv.z, dv.w};

    #pragma unroll
    for (int nt = 0; nt < 8; nt++) {
        f32x4 acc = {0.f, 0.f, 0.f, 0.f};
        #pragma unroll
        for (int kt = 0; kt < 4; kt++) {
            BF8 b;
            b.u4 = ((const uint4*)Wf)[(nt * 4 + kt) * 64 + lane];
            acc = __builtin_amdgcn_mfma_f32_16x16x32_bf16(a[kt].v, b.v, acc, 0, 0, 0);
        }
        int colg = nt * 16 + m;
        #pragma unroll
        for (int r = 0; r < 4; r++)
            Y[(size_t)(strip * 16 + quad * 4 + r) * DD + colg] = f2bf(acc[r] * dvr[r]);
    }
}

// ---------------- aggregation (R8-proven): 8 waves = 8 nodes/block ----------------
__global__ __launch_bounds__(512)
void k_agg2(const uint* __restrict__ H2,
            const int* __restrict__ row_ptr, const int* __restrict__ csr,
            const float* __restrict__ dinv,
            const float* __restrict__ bias, uint* __restrict__ Y2,
            float* __restrict__ psumG, float* __restrict__ psqG) {
    const int lane = threadIdx.x & 63;
    const int wid  = threadIdx.x >> 6;
    const int i = __builtin_amdgcn_readfirstlane(blockIdx.x * 8 + wid);
    const int p0 = row_ptr[i], p1 = row_ptr[i + 1];
    const float di = dinv[i];
    uint su = H2[(size_t)i * 64 + lane];
    float a0 = bflo(su), a1 = bfhi(su);            // self loop term g[i]
    float b0 = 0.f, b1 = 0.f, c0 = 0.f, c1 = 0.f, d0 = 0.f, d1 = 0.f;
    int p = p0;
    for (; p + 7 < p1; p += 8) {                   // 8 loads in flight
        int s0 = csr[p],     s1 = csr[p + 1], s2 = csr[p + 2], s3 = csr[p + 3];
        int s4 = csr[p + 4], s5 = csr[p + 5], s6 = csr[p + 6], s7 = csr[p + 7];
        uint h0 = H2[(size_t)s0 * 64 + lane];
        uint h1 = H2[(size_t)s1 * 64 + lane];
        uint h2 = H2[(size_t)s2 * 64 + lane];
        uint h3 = H2[(size_t)s3 * 64 + lane];
        uint h4 = H2[(size_t)s4 * 64 + lane];
        uint h5 = H2[(size_t)s5 * 64 + lane];
        uint h6 = H2[(size_t)s6 * 64 + lane];
        uint h7 = H2[(size_t)s7 * 64 + lane];
        a0 += bflo(h0); a1 += bfhi(h0);
        b0 += bflo(h1); b1 += bfhi(h1);
        c0 += bflo(h2); c1 += bfhi(h2);
        d0 += bflo(h3); d1 += bfhi(h3);
        a0 += bflo(h4); a1 += bfhi(h4);
        b0 += bflo(h5); b1 += bfhi(h5);
        c0 += bflo(h6); c1 += bfhi(h6);
        d0 += bflo(h7); d1 += bfhi(h7);
    }
    for (; p + 3 < p1; p += 4) {
        int s0 = csr[p], s1 = csr[p + 1], s2 = csr[p + 2], s3 = csr[p + 3];
        uint h0 = H2[(size_t)s0 * 64 + lane];
        uint h1 = H2[(size_t)s1 * 64 + lane];
        uint h2 = H2[(size_t)s2 * 64 + lane];
        uint h3 = H2[(size_t)s3 * 64 + lane];
        a0 += bflo(h0); a1 += bfhi(h0);
        b0 += bflo(h1); b1 += bfhi(h1);
        c0 += bflo(h2); c1 += bfhi(h2);
        d0 += bflo(h3); d1 += bfhi(h3);
    }
    for (; p < p1; p++) {
        uint h0 = H2[(size_t)csr[p] * 64 + lane];
        a0 += bflo(h0); a1 += bfhi(h0);
    }
    float2 bb = *(const float2*)(bias + 2 * lane);
    float r0 = fmaf((a0 + b0) + (c0 + d0), di, bb.x);
    float r1 = fmaf((a1 + b1) + (c1 + d1), di, bb.y);
    Y2[(size_t)i * 64 + lane] = (uint)f2bf(r0) | ((uint)f2bf(r1) << 16);

    // fused GraphNorm partial stats over the block's 8 nodes
    __shared__ float ls[8][128], lq[8][128];
    ls[wid][2 * lane]     = r0;      ls[wid][2 * lane + 1] = r1;
    lq[wid][2 * lane]     = r0 * r0; lq[wid][2 * lane + 1] = r1 * r1;
    __syncthreads();
    if (threadIdx.x < 128) {
        int f = threadIdx.x;
        float s = ((ls[0][f] + ls[1][f]) + (ls[2][f] + ls[3][f]))
                + ((ls[4][f] + ls[5][f]) + (ls[6][f] + ls[7][f]));
        float q = ((lq[0][f] + lq[1][f]) + (lq[2][f] + lq[3][f]))
                + ((lq[4][f] + lq[5][f]) + (lq[6][f] + lq[7][f]));
        int sh = (blockIdx.x & (NSHARD - 1)) * 128 + f;
        atomicAdd(&psumG[sh], s);
        atomicAdd(&psqG[sh], q);
    }
}

// ------- fused MLP head (MFMA): out = relu(T(norm(X))@W + b0h) @ v1 + b1 ; norm folded ------
__global__ __launch_bounds__(256)
void k_mlp(const uint* __restrict__ Xp, const ushort* __restrict__ Wf,
           const float* __restrict__ psum, const float* __restrict__ psq,
           const float* __restrict__ gw, const float* __restrict__ gb,
           const float* __restrict__ ga,
           const float* __restrict__ b0h, const float* __restrict__ v1,
           const float* __restrict__ b1, float* __restrict__ out) {
    __shared__ float smul[128], sadd[128];
    {
        int f = threadIdx.x;
        if (f < 128) {
            float s = 0.f, q = 0.f;
            #pragma unroll
            for (int sh = 0; sh < NSHARD; sh++) { s += psum[sh * 128 + f]; q += psq[sh * 128 + f]; }
            const float invn = 1.0f / (float)NN;
            float mm = s * invn, ex2 = q * invn, av = ga[f];
            float var = ex2 - mm * mm * (2.f * av - av * av);
            float inv = rsqrtf(var + EPSV);
            smul[f] = gw[f] * inv;
            sadd[f] = gb[f] - gw[f] * inv * av * mm;
        }
    }
    __syncthreads();
    int strip = blockIdx.x * 4 + (threadIdx.x >> 6);
    if (strip >= NSTRIP) return;
    int lane = threadIdx.x & 63;
    int quad = lane >> 4;
    int m = lane & 15;
    int row = strip * 16 + m;

    BF8 a[4];
    #pragma unroll
    for (int kt = 0; kt < 4; kt++) {
        int f = kt * 32 + quad * 8;
        uint4 xu = *(const uint4*)(Xp + (size_t)row * 64 + kt * 16 + quad * 4);
        float4 m0 = *(const float4*)(smul + f);
        float4 m1 = *(const float4*)(smul + f + 4);
        float4 a0 = *(const float4*)(sadd + f);
        float4 a1 = *(const float4*)(sadd + f + 4);
        uint xs[4] = {xu.x, xu.y, xu.z, xu.w};
        float mm[8] = {m0.x, m0.y, m0.z, m0.w, m1.x, m1.y, m1.z, m1.w};
        float aa[8] = {a0.x, a0.y, a0.z, a0.w, a1.x, a1.y, a1.z, a1.w};
        #pragma unroll
        for (int p = 0; p < 4; p++) {
            float lo = bflo(xs[p]), hi = bfhi(xs[p]);
            a[kt].us[2 * p]     = f2bf(fmaxf(0.f, fmaf(lo, mm[2 * p],     aa[2 * p])));
            a[kt].us[2 * p + 1] = f2bf(fmaxf(0.f, fmaf(hi, mm[2 * p + 1], aa[2 * p + 1])));
        }
    }

    float part[4] = {0.f, 0.f, 0.f, 0.f};
    #pragma unroll
    for (int nt = 0; nt < 8; nt++) {
        f32x4 acc = {0.f, 0.f, 0.f, 0.f};
        #pragma unroll
        for (int kt = 0; kt < 4; kt++) {
            BF8 b;
            b.u4 = ((const uint4*)Wf)[(nt * 4 + kt) * 64 + lane];
            acc = __builtin_amdgcn_mfma_f32_16x16x32_bf16(a[kt].v, b.v, acc, 0, 0, 0);
        }
        int colg = nt * 16 + m;
        float bb = b0h[colg];
        float vv = v1[colg];
        #pragma unroll
        for (int r = 0; r < 4; r++)
            part[r] = fmaf(fmaxf(0.f, acc[r] + bb), vv, part[r]);
    }
    #pragma unroll
    for (int r = 0; r < 4; r++) {
        #pragma unroll
        for (int off = 1; off < 16; off <<= 1)
            part[r] += __shfl_xor(part[r], off, 64);
    }
    if (m == 0) {
        float ob = b1[0];
        #pragma unroll
        for (int r = 0; r < 4; r++)
            out[strip * 16 + quad * 4 + r] = part[r] + ob;
    }
}

// ---------------- launch ----------------
static inline char* wsalloc(char*& p, size_t bytes) {
    char* r = p;
    p += (bytes + 255) & ~(size_t)255;
    return r;
}

extern "C" void kernel_launch(void* const* d_in, const int* in_sizes, int n_in,
                              void* d_out, int out_size, void* d_ws, size_t ws_size,
                              hipStream_t stream) {
    const float* x     = (const float*)d_in[0];
    const int*   ei    = (const int*)d_in[1];
    const int*   erow  = ei;
    const int*   ecol  = ei + NE;
    const float* W0    = (const float*)d_in[2];
    const float* b0    = (const float*)d_in[3];
    const float* W1    = (const float*)d_in[4];
    const float* b1    = (const float*)d_in[5];
    const float* gn0w  = (const float*)d_in[6];
    const float* gn0b  = (const float*)d_in[7];
    const float* gn0a  = (const float*)d_in[8];
    const float* gn1w  = (const float*)d_in[9];
    const float* gn1b  = (const float*)d_in[10];
    const float* gn1a  = (const float*)d_in[11];
    const float* lin0w = (const float*)d_in[12];
    const float* lin0b = (const float*)d_in[13];
    const float* lin1w = (const float*)d_in[14];
    const float* lin1b = (const float*)d_in[15];
    float* out = (float*)d_out;

    char* p = (char*)d_ws;
    ushort* bufA   = (ushort*)wsalloc(p, (size_t)NN * DD * 2);   // bf16 g = h*dinv
    ushort* bufB   = (ushort*)wsalloc(p, (size_t)NN * DD * 2);   // bf16 agg out
    int*    csr    = (int*)   wsalloc(p, (size_t)NE * 4);        // src only
    uint*   ebuf   = (uint*)  wsalloc(p, (size_t)NBUCK * CAP * 4); // padded buckets
    int*    cnt    = (int*)   wsalloc(p, 256 * 4);
    int*    row_ptr= (int*)   wsalloc(p, (size_t)(NN + 1) * 4);
    float*  dinv   = (float*) wsalloc(p, (size_t)NN * 4);
    float*  statsG = (float*) wsalloc(p, STATS_F * 4);
    ushort* Wf     = (ushort*)wsalloc(p, 3 * 2048 * 8 * 2);      // 3 prepped weights

    // 1) weight prep + zero scratch (cnt, statsG)
    k_prepw3<<<24, 256, 0, stream>>>(W0, W1, lin0w, Wf, cnt, statsG);
    ushort* Wf0 = Wf;
    ushort* Wf1 = Wf + 2048 * 8;
    ushort* Wf2 = Wf + 2 * 2048 * 8;

    // 2) FUSED hist+place into fixed-capacity buckets
    kb_histplace<<<NHB, 256, 0, stream>>>(erow, ecol, cnt, ebuf);

    // 3) per-bucket finalize (row_ptr / dinv / csr; global base from cnt-prefix)
    kb_fin<<<NBUCK, 512, 0, stream>>>(ebuf, cnt, row_ptr, dinv, csr);

    const int GB = (NSTRIP + 3) / 4;   // 1563 blocks for gemm-shaped kernels

    float* ps0 = statsG;
    float* pq0 = statsG + NSHARD * 128;
    float* ps1 = statsG + 2 * NSHARD * 128;
    float* pq1 = statsG + 3 * NSHARD * 128;

    // 4) GEMM1
    k_gemmA<<<GB, 256, 0, stream>>>(x, Wf0, dinv, bufA);

    // 5) aggregation stage 1
    k_agg2<<<NN / 8, 512, 0, stream>>>((const uint*)bufA, row_ptr, csr, dinv, b0,
                                       (uint*)bufB, ps0, pq0);

    // 6) GEMM2 (GraphNorm params folded into prologue)
    k_gemmB<<<GB, 256, 0, stream>>>((const uint*)bufB, Wf1, ps0, pq0,
                                    gn0w, gn0b, gn0a, dinv, bufA);

    // 7) aggregation stage 2
    k_agg2<<<NN / 8, 512, 0, stream>>>((const uint*)bufA, row_ptr, csr, dinv, b1,
                                       (uint*)bufB, ps1, pq1);

    // 8) fused MLP head (GraphNorm params folded into prologue)
    k_mlp<<<GB, 256, 0, stream>>>((const uint*)bufB, Wf2, ps1, pq1,
                                  gn1w, gn1b, gn1a,
                                  lin0b, lin1w, lin1b, out);

    (void)in_sizes; (void)n_in; (void)out_size; (void)ws_size;
}